// Round 3
// baseline (327.151 us; speedup 1.0000x reference)
//
#include <hip/hip_runtime.h>
#include <hip/hip_bf16.h>
#include <stdint.h>

// Problem constants (shapes fixed by the reference)
#define DIM 1024
#define NH 16
#define HD 64
#define S_ORIG 8704
#define WIN 512          // L * WINDOW = 256*2

typedef __attribute__((ext_vector_type(8))) short short8;
typedef __attribute__((ext_vector_type(4))) float f32x4;

__device__ __forceinline__ float bf2f(unsigned short u) {
    return __uint_as_float(((unsigned int)u) << 16);
}
__device__ __forceinline__ unsigned short f2bf(float f) {
    unsigned int x = __float_as_uint(f);
    unsigned int r = x + 0x7fffu + ((x >> 16) & 1u);   // RNE
    return (unsigned short)(r >> 16);
}
// two fp32 -> packed bf16x2 in ONE VALU op (T12 recipe; no builtin on gfx950)
__device__ __forceinline__ unsigned int cvtpk(float lo, float hi) {
    unsigned int r;
    asm("v_cvt_pk_bf16_f32 %0, %1, %2" : "=v"(r) : "v"(lo), "v"(hi));
    return r;
}
// exp2 in a single v_exp_f32 (log2e folded into the Q scale by the caller)
__device__ __forceinline__ float fexp2(float x) {
#if __has_builtin(__builtin_amdgcn_exp2f)
    return __builtin_amdgcn_exp2f(x);
#else
    float r;
    asm("v_exp_f32 %0, %1" : "=v"(r) : "v"(x));
    return r;
#endif
}

#define GLD_LDS(gptr, lptr) \
    __builtin_amdgcn_global_load_lds((const __attribute__((address_space(1))) void*)(gptr), \
                                     (__attribute__((address_space(3))) void*)(lptr), 16, 0, 0)

// ---------------- merged prep: fp32->bf16 convert (x) + weight transpose ----------------
// blocks [0, 8704): cvt; blocks [8704, 9728): transpose (one launch, one less bubble)
__global__ __launch_bounds__(256) void prep(const float* __restrict__ x,
                                            unsigned short* __restrict__ xb,
                                            const float* __restrict__ w0,
                                            const float* __restrict__ w1,
                                            const float* __restrict__ w2,
                                            const float* __restrict__ w3,
                                            unsigned short* __restrict__ wt) {
    __shared__ float ts[64][65];
    const int bx = blockIdx.x;
    const int t = threadIdx.x;
    if (bx < 8704) {
        int i = (bx * 256 + t) * 4;   // total = 8704*1024, exact
        float4 v = *(const float4*)(x + i);
        ushort4 o;
        o.x = f2bf(v.x); o.y = f2bf(v.y); o.z = f2bf(v.z); o.w = f2bf(v.w);
        *(ushort4*)(xb + i) = o;
        return;
    }
    const int b = bx - 8704;
    const int z = b >> 8;
    const int rem = b & 255;
    const int kb = (rem >> 4) * 64, nb = (rem & 15) * 64;
    const float* w = z == 0 ? w0 : z == 1 ? w1 : z == 2 ? w2 : w3;
    unsigned short* o = wt + (size_t)z * DIM * DIM;
    const int c = t & 63, r4 = t >> 6;
#pragma unroll
    for (int rr = 0; rr < 16; rr++) {
        int row = rr * 4 + r4;
        ts[row][c] = w[(size_t)(kb + row) * DIM + nb + c];
    }
    __syncthreads();
#pragma unroll
    for (int rr = 0; rr < 16; rr++) {
        int nl = rr * 4 + r4;
        o[(size_t)(nb + nl) * DIM + kb + c] = f2bf(ts[c][nl]);
    }
}

// ---------------- bf16 MFMA GEMM: C[M,N] = A[M,K] * Bt[N,K]^T + bias ----------------
// 128x128 tile, 4 waves, BK=32, global_load_lds width-16 staging + XOR bank swizzle.
// Grid is (m=68, n=8, z): consecutive linear blocks vary over m (XCD A-strip locality).
template <int OUTF32>
__global__ __launch_bounds__(256) void gemm_bf16(const unsigned short* __restrict__ A,
                                                 const unsigned short* __restrict__ Bt,
                                                 const float* __restrict__ b0,
                                                 const float* __restrict__ b1,
                                                 const float* __restrict__ b2,
                                                 void* __restrict__ Cout) {
    __shared__ __align__(16) unsigned short As[128 * 32];
    __shared__ __align__(16) unsigned short Bs[128 * 32];
    const int z = blockIdx.z;
    const unsigned short* B = Bt + (size_t)z * DIM * DIM;
    const float* bias = z == 0 ? b0 : (z == 1 ? b1 : b2);
    const int m0 = blockIdx.x * 128, n0 = blockIdx.y * 128;   // m fastest (XCD locality)
    const int tid = threadIdx.x;
    const int lane = tid & 63, wv = tid >> 6;
    const int wr = wv >> 1, wc = wv & 1;
    const int quad = lane >> 4, r = lane & 15;

    f32x4 acc[4][4];
#pragma unroll
    for (int i = 0; i < 4; i++)
#pragma unroll
        for (int j = 0; j < 4; j++)
#pragma unroll
            for (int t4 = 0; t4 < 4; t4++) acc[i][j][t4] = 0.0f;

    const unsigned short* a_base = A + (size_t)m0 * DIM;
    const unsigned short* b_base = B + (size_t)n0 * DIM;
    const int c0 = wv * 128 + lane;
    const int r0 = c0 >> 2, o0 = (((c0 & 3) ^ ((c0 >> 3) & 3))) * 8;
    const int c1 = c0 + 64;
    const int r1 = c1 >> 2, o1 = (((c1 & 3) ^ ((c1 >> 3) & 3))) * 8;
    unsigned short* lA0 = &As[(size_t)(wv * 128) * 8];
    unsigned short* lA1 = &As[(size_t)(wv * 128 + 64) * 8];
    unsigned short* lB0 = &Bs[(size_t)(wv * 128) * 8];
    unsigned short* lB1 = &Bs[(size_t)(wv * 128 + 64) * 8];

    const int jsw = (quad ^ ((r >> 1) & 3)) * 8;

    for (int k0 = 0; k0 < DIM; k0 += 32) {
        __syncthreads();   // previous iteration's frag readers done before DMA overwrites
        GLD_LDS(a_base + (size_t)r0 * DIM + k0 + o0, lA0);
        GLD_LDS(a_base + (size_t)r1 * DIM + k0 + o1, lA1);
        GLD_LDS(b_base + (size_t)r0 * DIM + k0 + o0, lB0);
        GLD_LDS(b_base + (size_t)r1 * DIM + k0 + o1, lB1);
        __syncthreads();   // vmcnt(0) drain
        short8 af[4], bfr[4];
#pragma unroll
        for (int i = 0; i < 4; i++)
            af[i] = *(const short8*)&As[(wr * 64 + i * 16 + r) * 32 + jsw];
#pragma unroll
        for (int j = 0; j < 4; j++)
            bfr[j] = *(const short8*)&Bs[(wc * 64 + j * 16 + r) * 32 + jsw];
#pragma unroll
        for (int i = 0; i < 4; i++)
#pragma unroll
            for (int j = 0; j < 4; j++)
                acc[i][j] = __builtin_amdgcn_mfma_f32_16x16x32_bf16(af[i], bfr[j], acc[i][j], 0, 0, 0);
    }

    // epilogue: C/D layout col = lane&15, row = quad*4 + reg
#pragma unroll
    for (int i = 0; i < 4; i++) {
        const int row = m0 + wr * 64 + i * 16 + quad * 4;
#pragma unroll
        for (int j = 0; j < 4; j++) {
            const int col = n0 + wc * 64 + j * 16 + r;
            const float bvl = bias[col];
#pragma unroll
            for (int t4 = 0; t4 < 4; t4++) {
                float vv = acc[i][j][t4] + bvl;
                if (OUTF32) {
                    ((float*)Cout)[(size_t)(row + t4) * DIM + col] = vv;
                } else {
                    ((unsigned short*)Cout)[(size_t)z * S_ORIG * DIM + (size_t)(row + t4) * DIM + col] = f2bf(vv);
                }
            }
        }
    }
}

// ---------------- fused RMSNorm + RoPE, wave-per-row (no LDS, no barrier) ----------------
__global__ __launch_bounds__(256) void norm_rope(unsigned short* __restrict__ hq,
                                                 unsigned short* __restrict__ hk,
                                                 const float* __restrict__ gq,
                                                 const float* __restrict__ gk,
                                                 const float* __restrict__ fcos,
                                                 const float* __restrict__ fsin) {
    const int z = blockIdx.y;
    unsigned short* h = z == 0 ? hq : hk;
    const float* g = z == 0 ? gq : gk;
    const int w = threadIdx.x >> 6, lane = threadIdx.x & 63;
    const int srow = blockIdx.x * 4 + w;
    unsigned short* hp = h + (size_t)srow * DIM;
    const int p0 = lane * 8, p1 = 512 + lane * 8;

    union { int4 i4; unsigned short u[8]; } r0, r1, o0, o1;
    r0.i4 = *(const int4*)(hp + p0);
    r1.i4 = *(const int4*)(hp + p1);
    float v[16];
#pragma unroll
    for (int j = 0; j < 8; j++) { v[j] = bf2f(r0.u[j]); v[8 + j] = bf2f(r1.u[j]); }

    float ss = 0.0f;
#pragma unroll
    for (int j = 0; j < 16; j++) ss += v[j] * v[j];
#pragma unroll
    for (int off = 1; off < 64; off <<= 1) ss += __shfl_xor(ss, off, 64);
    const float rinv = rsqrtf(ss * (1.0f / DIM) + 1e-6f);

    float4 ga = *(const float4*)(g + p0), gb = *(const float4*)(g + p0 + 4);
    float4 gc = *(const float4*)(g + p1), gd = *(const float4*)(g + p1 + 4);
    const float* gg[4] = {&ga.x, &gb.x, &gc.x, &gd.x};
#pragma unroll
    for (int q4 = 0; q4 < 4; q4++)
#pragma unroll
        for (int j = 0; j < 4; j++) v[q4 * 4 + j] *= rinv * gg[q4][j];

    const int i0 = (p0 & 63) >> 1;   // pair base within head (mult of 4); same for p1
    float4 cs = *(const float4*)(fcos + (size_t)srow * 32 + i0);
    float4 sn = *(const float4*)(fsin + (size_t)srow * 32 + i0);
    const float* cp = &cs.x;
    const float* sp = &sn.x;
#pragma unroll
    for (int seg = 0; seg < 2; seg++) {
        unsigned short* uo = seg == 0 ? o0.u : o1.u;
#pragma unroll
        for (int pr = 0; pr < 4; pr++) {
            const float a = v[seg * 8 + pr * 2], b = v[seg * 8 + pr * 2 + 1];
            uo[pr * 2]     = f2bf(a * cp[pr] - b * sp[pr]);
            uo[pr * 2 + 1] = f2bf(a * sp[pr] + b * cp[pr]);
        }
    }
    *(int4*)(hp + p0) = o0.i4;
    *(int4*)(hp + p1) = o1.i4;
}

// ---------------- dilated sliding-window attention, transposed-MFMA flash ----------------
// R3 change: K/V fragment loads HOISTED out of qstep — identical for both q-tiles of the
// pair, so read LDS once per staged tile (16 b128 instead of 32) and hold in registers.
// V-stage writes via ds_write2_b32 (two rows per instruction, offset1 = 144B/4 = 36).
// LDS ops per tile-iter per wave: ~60 -> ~36 (theory: attn is LDS-pipe-bound).
__device__ __forceinline__ void qstep(const short8* __restrict__ kf,
                                      const short8* __restrict__ vf,
                                      unsigned short* __restrict__ pw,
                                      int quad, int r16,
                                      int kbase, int qi, bool edge,
                                      const short8* __restrict__ qf,
                                      f32x4* __restrict__ oacc, float& lsum) {
    // --- S^T[kk][q]: A-op = K rows (in regs), B-op = Q frag ---
    f32x4 sv[4];
#pragma unroll
    for (int nt = 0; nt < 4; nt++) {
        f32x4 a = {0.0f, 0.0f, 0.0f, 0.0f};
        a = __builtin_amdgcn_mfma_f32_16x16x32_bf16(kf[2 * nt], qf[0], a, 0, 0, 0);
        a = __builtin_amdgcn_mfma_f32_16x16x32_bf16(kf[2 * nt + 1], qf[1], a, 0, 0, 0);
        sv[nt] = a;
    }
    // --- exp2 (no max subtraction: scores bounded), mask on edge tiles only ---
#pragma unroll
    for (int nt = 0; nt < 4; nt++) {
        float p[4];
#pragma unroll
        for (int rr = 0; rr < 4; rr++) {
            float e = fexp2(sv[nt][rr]);
            if (edge) {
                const int kj = kbase + nt * 16 + quad * 4 + rr;
                const int dl = qi - kj;
                if (dl > WIN || dl < -WIN) e = 0.0f;
            }
            p[rr] = e;
        }
        lsum += (p[0] + p[1]) + (p[2] + p[3]);
        uint2 pk;
        pk.x = cvtpk(p[0], p[1]);
        pk.y = cvtpk(p[2], p[3]);
        *(uint2*)&pw[r16 * 72 + nt * 16 + quad * 4] = pk;
    }
    __asm__ volatile("s_waitcnt lgkmcnt(0)" ::: "memory");
    // --- O^T += V^T * P^T (V frags in regs) ---
    short8 pf0 = *(const short8*)&pw[r16 * 72 + quad * 8];
    short8 pf1 = *(const short8*)&pw[r16 * 72 + 32 + quad * 8];
#pragma unroll
    for (int nt = 0; nt < 4; nt++) {
        oacc[nt] = __builtin_amdgcn_mfma_f32_16x16x32_bf16(vf[2 * nt], pf0, oacc[nt], 0, 0, 0);
        oacc[nt] = __builtin_amdgcn_mfma_f32_16x16x32_bf16(vf[2 * nt + 1], pf1, oacc[nt], 0, 0, 0);
    }
}

__global__ __launch_bounds__(256) void attn(const unsigned short* __restrict__ qkv,
                                            unsigned short* __restrict__ ob) {
    __shared__ __align__(16) unsigned short Ks[64 * 64];        // swizzled, GLD_LDS-staged
    __shared__ __align__(16) unsigned short Vt[64 * 72];
    __shared__ __align__(16) unsigned short Ps[4][16 * 72];

    const int head = blockIdx.x >> 1;
    const int d = blockIdx.x & 1;
    const int t0 = blockIdx.y * 2, t1 = t0 + 1;     // q-tile pair
    const int tid = threadIdx.x;
    const int lane = tid & 63, wv = tid >> 6;
    const int quad = lane >> 4, r16 = lane & 15;

    const unsigned short* qb = qkv;
    const unsigned short* kb = qkv + (size_t)S_ORIG * DIM;
    const unsigned short* vb = qkv + (size_t)2 * S_ORIG * DIM;

    // --- this lane's queries (B-operand of S^T), both tiles of the pair ---
    // scale = 1/8 (softmax) * log2(e) so the in-loop exp is a bare v_exp_f32 (2^x)
    const int qi0 = t0 * 64 + wv * 16 + r16;
    const int qi1 = qi0 + 64;
    const int og_q0 = ((qi0 >> 8) << 9) + d * 256 + (qi0 & 255);
    const int og_q1 = ((qi1 >> 8) << 9) + d * 256 + (qi1 & 255);
    short8 qf0[2], qf1[2];
    {
        const float QSC = 0.125f * 1.44269504088896f;
        const unsigned short* qr0 = qb + (size_t)og_q0 * DIM + head * HD + quad * 8;
        const unsigned short* qr1 = qb + (size_t)og_q1 * DIM + head * HD + quad * 8;
#pragma unroll
        for (int c = 0; c < 2; c++) {
            union { int4 i4; unsigned short u[8]; short8 s8; } i0v, i1v, a0v, a1v;
            i0v.i4 = *(const int4*)(qr0 + c * 32);
            i1v.i4 = *(const int4*)(qr1 + c * 32);
#pragma unroll
            for (int j = 0; j < 8; j++) {
                a0v.u[j] = f2bf(bf2f(i0v.u[j]) * QSC);
                a1v.u[j] = f2bf(bf2f(i1v.u[j]) * QSC);
            }
            qf0[c] = a0v.s8;
            qf1[c] = a1v.s8;
        }
    }

    f32x4 oacc0[4], oacc1[4];
    float lsum0 = 0.0f, lsum1 = 0.0f;
#pragma unroll
    for (int nt = 0; nt < 4; nt++)
#pragma unroll
        for (int rr = 0; rr < 4; rr++) { oacc0[nt][rr] = 0.0f; oacc1[nt][rr] = 0.0f; }

    // union of both windows, real tiles only (kt>=68 all-zero pad handled analytically)
    const int kt_lo = (t0 - 8 > 0) ? (t0 - 8) : 0;
    const int kt_hi = (t1 + 8 < 67) ? (t1 + 8) : 67;

    // K staging via GLD_LDS: chunk c = h*256 + tid; row = c>>3, physical slot c&7 holds
    // global chunk (c&7)^(row&7). Wave-uniform LDS base, per-lane swizzled source.
    const int krow0 = tid >> 3;                          // h=0 rows 0..31; h=1: +32
    const int kgc = ((tid & 7) ^ (krow0 & 7)) * 8;       // source chunk elem offset
    unsigned short* kdst0 = &Ks[(size_t)(wv * 64) * 8];
    unsigned short* kdst1 = &Ks[(size_t)(256 + wv * 64) * 8];

    // V^T staging coords
    const int vt_kk = (tid & 31) * 2, vt_d0 = (tid >> 5) * 8;
    const int vbase_addr = (vt_d0 * 72 + vt_kk) * 2 + (int)(size_t)&Vt[0];  // LDS byte addr

    // frag-read swizzled chunk offsets: global chunk j of row r lives at j^(r&7)
    const int jsw0 = (quad ^ (r16 & 7)) * 8;
    const int jsw1 = jsw0 ^ 32;

    unsigned short* pw = &Ps[wv][0];

    for (int kt = kt_lo; kt <= kt_hi; kt++) {
        const int kbase = kt * 64;
        __syncthreads();   // previous tile's frag readers done before overwrite

        // stage K via DMA (2 instrs), source pre-swizzled within each 128B row
        {
            const int kj0 = kbase + krow0;
            const int ok0 = ((kj0 >> 8) << 9) + d * 256 + (kj0 & 255);
            GLD_LDS(kb + (size_t)ok0 * DIM + head * HD + kgc, kdst0);
            const int kj1 = kj0 + 32;
            const int ok1 = ((kj1 >> 8) << 9) + d * 256 + (kj1 & 255);
            GLD_LDS(kb + (size_t)ok1 * DIM + head * HD + kgc, kdst1);
        }
        // stage V transposed: Vt[d][kk]; halfword merge via v_perm, paired-row store
        // via ds_write2_b32 (rows d and d+1 at same kk: +144B = offset1:36 dwords)
        {
            const int kj0 = kbase + vt_kk;
            const int ok0 = ((kj0 >> 8) << 9) + d * 256 + (kj0 & 255);
            union { int4 i4; unsigned int w[4]; } a0, a1;
            a0.i4 = *(const int4*)(vb + (size_t)ok0 * DIM + head * HD + vt_d0);
            a1.i4 = *(const int4*)(vb + (size_t)(ok0 + 1) * DIM + head * HD + vt_d0);
#pragma unroll
            for (int dw = 0; dw < 4; dw++) {
                unsigned int lo = __builtin_amdgcn_perm(a1.w[dw], a0.w[dw], 0x05040100u);
                unsigned int hi = __builtin_amdgcn_perm(a1.w[dw], a0.w[dw], 0x07060302u);
                __asm__ volatile("ds_write2_b32 %0, %1, %2 offset0:0 offset1:36"
                                 :: "v"(vbase_addr + dw * 288), "v"(lo), "v"(hi)
                                 : "memory");
            }
        }
        __syncthreads();   // vmcnt(0)+lgkmcnt(0) drain

        // --- hoisted fragment loads: once per tile, reused by both qsteps ---
        short8 kf[8], vf[8];
#pragma unroll
        for (int nt = 0; nt < 4; nt++) {
            kf[2 * nt]     = *(const short8*)&Ks[(nt * 16 + r16) * 64 + jsw0];
            kf[2 * nt + 1] = *(const short8*)&Ks[(nt * 16 + r16) * 64 + jsw1];
            vf[2 * nt]     = *(const short8*)&Vt[(nt * 16 + r16) * 72 + quad * 8];
            vf[2 * nt + 1] = *(const short8*)&Vt[(nt * 16 + r16) * 72 + 32 + quad * 8];
        }

        // qset0 active for kt in [t0-8, t0+8]; qset1 for [t1-8, t1+8]; both uniform
        if (kt <= t0 + 8)
            qstep(kf, vf, pw, quad, r16, kbase, qi0,
                  (kt == t0 - 8) || (kt == t0 + 8), qf0, oacc0, lsum0);
        if (kt >= t1 - 8)
            qstep(kf, vf, pw, quad, r16, kbase, qi1,
                  (kt == t1 - 8) || (kt == t1 + 8), qf1, oacc1, lsum1);
    }

    // --- final l: reduce across the 4 quads (other lanes hold other kk of same q) ---
    lsum0 += __shfl_xor(lsum0, 16, 64);
    lsum0 += __shfl_xor(lsum0, 32, 64);
    lsum1 += __shfl_xor(lsum1, 16, 64);
    lsum1 += __shfl_xor(lsum1, 32, 64);
    // zero-pad keys (dilated pos >= 4352 -> orig >= 8704, K=V=0): score 0 -> exp2(0)=1
    {
        const int cnt0 = (qi0 + WIN < 4607 ? qi0 + WIN : 4607) - 4351;
        if (cnt0 > 0) lsum0 += (float)cnt0;
        const int cnt1 = (qi1 + WIN < 4607 ? qi1 + WIN : 4607) - 4351;
        if (cnt1 > 0) lsum1 += (float)cnt1;
    }
    const float linv0 = 1.0f / lsum0;
    const float linv1 = 1.0f / lsum1;

    // --- write O: lane owns q = r16; 4 consecutive dims per nt; both qsets ---
#pragma unroll
    for (int nt = 0; nt < 4; nt++) {
        ushort4 o0, o1;
        o0.x = f2bf(oacc0[nt][0] * linv0);
        o0.y = f2bf(oacc0[nt][1] * linv0);
        o0.z = f2bf(oacc0[nt][2] * linv0);
        o0.w = f2bf(oacc0[nt][3] * linv0);
        *(ushort4*)&ob[(size_t)og_q0 * DIM + head * HD + nt * 16 + quad * 4] = o0;
        o1.x = f2bf(oacc1[nt][0] * linv1);
        o1.y = f2bf(oacc1[nt][1] * linv1);
        o1.z = f2bf(oacc1[nt][2] * linv1);
        o1.w = f2bf(oacc1[nt][3] * linv1);
        *(ushort4*)&ob[(size_t)og_q1 * DIM + head * HD + nt * 16 + quad * 4] = o1;
    }
}

// ---------------- launch ----------------
extern "C" void kernel_launch(void* const* d_in, const int* in_sizes, int n_in,
                              void* d_out, int out_size, void* d_ws, size_t ws_size,
                              hipStream_t stream) {
    const float* x    = (const float*)d_in[0];
    const float* fcos = (const float*)d_in[1];
    const float* fsin = (const float*)d_in[2];
    const float* wq   = (const float*)d_in[3];
    const float* bq   = (const float*)d_in[4];
    const float* wk   = (const float*)d_in[5];
    const float* bk   = (const float*)d_in[6];
    const float* wv   = (const float*)d_in[7];
    const float* bv   = (const float*)d_in[8];
    const float* wo   = (const float*)d_in[9];
    const float* bo   = (const float*)d_in[10];
    const float* gq   = (const float*)d_in[11];
    const float* gk   = (const float*)d_in[12];

    char* ws = (char*)d_ws;
    unsigned short* xb = (unsigned short*)(ws);
    unsigned short* wt = (unsigned short*)(ws + 17825792);
    unsigned short* h  = (unsigned short*)(ws + 26214400);
    unsigned short* ob = (unsigned short*)(ws + 79691776);
    float* outp = (float*)d_out;

    prep<<<9728, 256, 0, stream>>>(x, xb, wq, wk, wv, wo, wt);
    gemm_bf16<0><<<dim3(68, 8, 3), 256, 0, stream>>>(xb, wt, bq, bk, bv, (void*)h);
    norm_rope<<<dim3(2176, 2), 256, 0, stream>>>(h, h + (size_t)S_ORIG * DIM, gq, gk, fcos, fsin);
    attn<<<dim3(32, 34), 256, 0, stream>>>(h, ob);
    gemm_bf16<1><<<dim3(68, 8, 1), 256, 0, stream>>>(ob, wt + (size_t)3 * DIM * DIM, bo, bo, bo, (void*)outp);
}

// Round 4
// 312.204 us; speedup vs baseline: 1.0479x; 1.0479x over previous
//
#include <hip/hip_runtime.h>
#include <hip/hip_bf16.h>
#include <stdint.h>

// Problem constants (shapes fixed by the reference)
#define DIM 1024
#define NH 16
#define HD 64
#define S_ORIG 8704
#define WIN 512          // L * WINDOW = 256*2

typedef __attribute__((ext_vector_type(8))) short short8;
typedef __attribute__((ext_vector_type(4))) float f32x4;

__device__ __forceinline__ float bf2f(unsigned short u) {
    return __uint_as_float(((unsigned int)u) << 16);
}
__device__ __forceinline__ unsigned short f2bf(float f) {
    unsigned int x = __float_as_uint(f);
    unsigned int r = x + 0x7fffu + ((x >> 16) & 1u);   // RNE
    return (unsigned short)(r >> 16);
}
// two fp32 -> packed bf16x2 in ONE VALU op (T12 recipe; no builtin on gfx950)
__device__ __forceinline__ unsigned int cvtpk(float lo, float hi) {
    unsigned int r;
    asm("v_cvt_pk_bf16_f32 %0, %1, %2" : "=v"(r) : "v"(lo), "v"(hi));
    return r;
}
// exp2 in a single v_exp_f32 (log2e folded into the Q scale by the caller)
__device__ __forceinline__ float fexp2(float x) {
#if __has_builtin(__builtin_amdgcn_exp2f)
    return __builtin_amdgcn_exp2f(x);
#else
    float r;
    asm("v_exp_f32 %0, %1" : "=v"(r) : "v"(x));
    return r;
#endif
}

#define GLD_LDS(gptr, lptr) \
    __builtin_amdgcn_global_load_lds((const __attribute__((address_space(1))) void*)(gptr), \
                                     (__attribute__((address_space(3))) void*)(lptr), 16, 0, 0)

// raw barrier (no compiler-inserted full drains) with compiler memory fences
#define FBAR() do { __asm__ volatile("" ::: "memory"); \
                    __builtin_amdgcn_s_barrier(); \
                    __asm__ volatile("" ::: "memory"); } while (0)

// ---------------- merged prep: fp32->bf16 convert (x) + weight transpose ----------------
// blocks [0, 8704): cvt; blocks [8704, 9728): transpose (one launch, one less bubble)
__global__ __launch_bounds__(256) void prep(const float* __restrict__ x,
                                            unsigned short* __restrict__ xb,
                                            const float* __restrict__ w0,
                                            const float* __restrict__ w1,
                                            const float* __restrict__ w2,
                                            const float* __restrict__ w3,
                                            unsigned short* __restrict__ wt) {
    __shared__ float ts[64][65];
    const int bx = blockIdx.x;
    const int t = threadIdx.x;
    if (bx < 8704) {
        int i = (bx * 256 + t) * 4;   // total = 8704*1024, exact
        float4 v = *(const float4*)(x + i);
        ushort4 o;
        o.x = f2bf(v.x); o.y = f2bf(v.y); o.z = f2bf(v.z); o.w = f2bf(v.w);
        *(ushort4*)(xb + i) = o;
        return;
    }
    const int b = bx - 8704;
    const int z = b >> 8;
    const int rem = b & 255;
    const int kb = (rem >> 4) * 64, nb = (rem & 15) * 64;
    const float* w = z == 0 ? w0 : z == 1 ? w1 : z == 2 ? w2 : w3;
    unsigned short* o = wt + (size_t)z * DIM * DIM;
    const int c = t & 63, r4 = t >> 6;
#pragma unroll
    for (int rr = 0; rr < 16; rr++) {
        int row = rr * 4 + r4;
        ts[row][c] = w[(size_t)(kb + row) * DIM + nb + c];
    }
    __syncthreads();
#pragma unroll
    for (int rr = 0; rr < 16; rr++) {
        int nl = rr * 4 + r4;
        o[(size_t)(nb + nl) * DIM + kb + c] = f2bf(ts[c][nl]);
    }
}

// ---------------- bf16 MFMA GEMM: C[M,N] = A[M,K] * Bt[N,K]^T + bias ----------------
// 128x128 tile, 4 waves, BK=32, global_load_lds width-16 staging + XOR bank swizzle.
// Grid is (m=68, n=8, z): consecutive linear blocks vary over m (XCD A-strip locality).
template <int OUTF32>
__global__ __launch_bounds__(256) void gemm_bf16(const unsigned short* __restrict__ A,
                                                 const unsigned short* __restrict__ Bt,
                                                 const float* __restrict__ b0,
                                                 const float* __restrict__ b1,
                                                 const float* __restrict__ b2,
                                                 void* __restrict__ Cout) {
    __shared__ __align__(16) unsigned short As[128 * 32];
    __shared__ __align__(16) unsigned short Bs[128 * 32];
    const int z = blockIdx.z;
    const unsigned short* B = Bt + (size_t)z * DIM * DIM;
    const float* bias = z == 0 ? b0 : (z == 1 ? b1 : b2);
    const int m0 = blockIdx.x * 128, n0 = blockIdx.y * 128;   // m fastest (XCD locality)
    const int tid = threadIdx.x;
    const int lane = tid & 63, wv = tid >> 6;
    const int wr = wv >> 1, wc = wv & 1;
    const int quad = lane >> 4, r = lane & 15;

    f32x4 acc[4][4];
#pragma unroll
    for (int i = 0; i < 4; i++)
#pragma unroll
        for (int j = 0; j < 4; j++)
#pragma unroll
            for (int t4 = 0; t4 < 4; t4++) acc[i][j][t4] = 0.0f;

    const unsigned short* a_base = A + (size_t)m0 * DIM;
    const unsigned short* b_base = B + (size_t)n0 * DIM;
    const int c0 = wv * 128 + lane;
    const int r0 = c0 >> 2, o0 = (((c0 & 3) ^ ((c0 >> 3) & 3))) * 8;
    const int c1 = c0 + 64;
    const int r1 = c1 >> 2, o1 = (((c1 & 3) ^ ((c1 >> 3) & 3))) * 8;
    unsigned short* lA0 = &As[(size_t)(wv * 128) * 8];
    unsigned short* lA1 = &As[(size_t)(wv * 128 + 64) * 8];
    unsigned short* lB0 = &Bs[(size_t)(wv * 128) * 8];
    unsigned short* lB1 = &Bs[(size_t)(wv * 128 + 64) * 8];

    const int jsw = (quad ^ ((r >> 1) & 3)) * 8;

    for (int k0 = 0; k0 < DIM; k0 += 32) {
        __syncthreads();   // previous iteration's frag readers done before DMA overwrites
        GLD_LDS(a_base + (size_t)r0 * DIM + k0 + o0, lA0);
        GLD_LDS(a_base + (size_t)r1 * DIM + k0 + o1, lA1);
        GLD_LDS(b_base + (size_t)r0 * DIM + k0 + o0, lB0);
        GLD_LDS(b_base + (size_t)r1 * DIM + k0 + o1, lB1);
        __syncthreads();   // vmcnt(0) drain
        short8 af[4], bfr[4];
#pragma unroll
        for (int i = 0; i < 4; i++)
            af[i] = *(const short8*)&As[(wr * 64 + i * 16 + r) * 32 + jsw];
#pragma unroll
        for (int j = 0; j < 4; j++)
            bfr[j] = *(const short8*)&Bs[(wc * 64 + j * 16 + r) * 32 + jsw];
#pragma unroll
        for (int i = 0; i < 4; i++)
#pragma unroll
            for (int j = 0; j < 4; j++)
                acc[i][j] = __builtin_amdgcn_mfma_f32_16x16x32_bf16(af[i], bfr[j], acc[i][j], 0, 0, 0);
    }

    // epilogue: C/D layout col = lane&15, row = quad*4 + reg
#pragma unroll
    for (int i = 0; i < 4; i++) {
        const int row = m0 + wr * 64 + i * 16 + quad * 4;
#pragma unroll
        for (int j = 0; j < 4; j++) {
            const int col = n0 + wc * 64 + j * 16 + r;
            const float bvl = bias[col];
#pragma unroll
            for (int t4 = 0; t4 < 4; t4++) {
                float vv = acc[i][j][t4] + bvl;
                if (OUTF32) {
                    ((float*)Cout)[(size_t)(row + t4) * DIM + col] = vv;
                } else {
                    ((unsigned short*)Cout)[(size_t)z * S_ORIG * DIM + (size_t)(row + t4) * DIM + col] = f2bf(vv);
                }
            }
        }
    }
}

// ---------------- fused RMSNorm + RoPE, wave-per-row (no LDS, no barrier) ----------------
__global__ __launch_bounds__(256) void norm_rope(unsigned short* __restrict__ hq,
                                                 unsigned short* __restrict__ hk,
                                                 const float* __restrict__ gq,
                                                 const float* __restrict__ gk,
                                                 const float* __restrict__ fcos,
                                                 const float* __restrict__ fsin) {
    const int z = blockIdx.y;
    unsigned short* h = z == 0 ? hq : hk;
    const float* g = z == 0 ? gq : gk;
    const int w = threadIdx.x >> 6, lane = threadIdx.x & 63;
    const int srow = blockIdx.x * 4 + w;
    unsigned short* hp = h + (size_t)srow * DIM;
    const int p0 = lane * 8, p1 = 512 + lane * 8;

    union { int4 i4; unsigned short u[8]; } r0, r1, o0, o1;
    r0.i4 = *(const int4*)(hp + p0);
    r1.i4 = *(const int4*)(hp + p1);
    float v[16];
#pragma unroll
    for (int j = 0; j < 8; j++) { v[j] = bf2f(r0.u[j]); v[8 + j] = bf2f(r1.u[j]); }

    float ss = 0.0f;
#pragma unroll
    for (int j = 0; j < 16; j++) ss += v[j] * v[j];
#pragma unroll
    for (int off = 1; off < 64; off <<= 1) ss += __shfl_xor(ss, off, 64);
    const float rinv = rsqrtf(ss * (1.0f / DIM) + 1e-6f);

    float4 ga = *(const float4*)(g + p0), gb = *(const float4*)(g + p0 + 4);
    float4 gc = *(const float4*)(g + p1), gd = *(const float4*)(g + p1 + 4);
    const float* gg[4] = {&ga.x, &gb.x, &gc.x, &gd.x};
#pragma unroll
    for (int q4 = 0; q4 < 4; q4++)
#pragma unroll
        for (int j = 0; j < 4; j++) v[q4 * 4 + j] *= rinv * gg[q4][j];

    const int i0 = (p0 & 63) >> 1;   // pair base within head (mult of 4); same for p1
    float4 cs = *(const float4*)(fcos + (size_t)srow * 32 + i0);
    float4 sn = *(const float4*)(fsin + (size_t)srow * 32 + i0);
    const float* cp = &cs.x;
    const float* sp = &sn.x;
#pragma unroll
    for (int seg = 0; seg < 2; seg++) {
        unsigned short* uo = seg == 0 ? o0.u : o1.u;
#pragma unroll
        for (int pr = 0; pr < 4; pr++) {
            const float a = v[seg * 8 + pr * 2], b = v[seg * 8 + pr * 2 + 1];
            uo[pr * 2]     = f2bf(a * cp[pr] - b * sp[pr]);
            uo[pr * 2 + 1] = f2bf(a * sp[pr] + b * cp[pr]);
        }
    }
    *(int4*)(hp + p0) = o0.i4;
    *(int4*)(hp + p1) = o1.i4;
}

// ---------------- dilated sliding-window attention, transposed-MFMA flash ----------------
// R4: software-pipelined staging (T3/T4-lite). K double-buffered via GLD_LDS DMA; V global
// loads issued one tile ahead into registers (T14 issue-early/write-late). Counted
// s_waitcnt vmcnt(4) instead of a vmcnt(0) drain: each iter issues exactly 4 vector-mem
// ops (2 K-DMA + 2 V-loads), so vmcnt(4) completes precisely the previous tile's 4 while
// this tile's stay in flight across both raw s_barriers. Two q-tiles per block (R2).
// Per-lane softmax via swapped QK^T; fixed-max exp2 (scores bounded, log2e in Q scale);
// zero-pad keys (kt>=68) contribute l analytically.
__device__ __forceinline__ void qstep(const unsigned short* __restrict__ Ks,
                                      const unsigned short* __restrict__ Vt,
                                      unsigned short* __restrict__ pw,
                                      int jsw0, int jsw1, int quad, int r16,
                                      int kbase, int qi, bool edge,
                                      const short8* __restrict__ qf,
                                      f32x4* __restrict__ oacc, float& lsum) {
    // --- S^T[kk][q]: A-op = K rows (swizzled read), B-op = Q frag ---
    f32x4 sv[4];
#pragma unroll
    for (int nt = 0; nt < 4; nt++) {
        const int row = (nt * 16 + r16) * 64;
        short8 k0f = *(const short8*)&Ks[row + jsw0];
        short8 k1f = *(const short8*)&Ks[row + jsw1];
        f32x4 a = {0.0f, 0.0f, 0.0f, 0.0f};
        a = __builtin_amdgcn_mfma_f32_16x16x32_bf16(k0f, qf[0], a, 0, 0, 0);
        a = __builtin_amdgcn_mfma_f32_16x16x32_bf16(k1f, qf[1], a, 0, 0, 0);
        sv[nt] = a;
    }
    // --- exp2 (no max subtraction: scores bounded), mask on edge tiles only ---
#pragma unroll
    for (int nt = 0; nt < 4; nt++) {
        float p[4];
#pragma unroll
        for (int rr = 0; rr < 4; rr++) {
            float e = fexp2(sv[nt][rr]);
            if (edge) {
                const int kj = kbase + nt * 16 + quad * 4 + rr;
                const int dl = qi - kj;
                if (dl > WIN || dl < -WIN) e = 0.0f;
            }
            p[rr] = e;
        }
        lsum += (p[0] + p[1]) + (p[2] + p[3]);
        uint2 pk;
        pk.x = cvtpk(p[0], p[1]);
        pk.y = cvtpk(p[2], p[3]);
        *(uint2*)&pw[r16 * 72 + nt * 16 + quad * 4] = pk;
    }
    __asm__ volatile("s_waitcnt lgkmcnt(0)" ::: "memory");
    // --- O^T += V^T * P^T ---
    short8 pf0 = *(const short8*)&pw[r16 * 72 + quad * 8];
    short8 pf1 = *(const short8*)&pw[r16 * 72 + 32 + quad * 8];
#pragma unroll
    for (int nt = 0; nt < 4; nt++) {
        short8 v0f = *(const short8*)&Vt[(nt * 16 + r16) * 72 + quad * 8];
        short8 v1f = *(const short8*)&Vt[(nt * 16 + r16) * 72 + 32 + quad * 8];
        oacc[nt] = __builtin_amdgcn_mfma_f32_16x16x32_bf16(v0f, pf0, oacc[nt], 0, 0, 0);
        oacc[nt] = __builtin_amdgcn_mfma_f32_16x16x32_bf16(v1f, pf1, oacc[nt], 0, 0, 0);
    }
}

__device__ __forceinline__ void pack_write_v(unsigned short* __restrict__ Vt,
                                             int4 a0i, int4 a1i, int vt_d0, int vt_kk) {
    union { int4 i4; unsigned int w[4]; } a0, a1;
    a0.i4 = a0i; a1.i4 = a1i;
#pragma unroll
    for (int dw = 0; dw < 4; dw++) {
        unsigned int lo = __builtin_amdgcn_perm(a1.w[dw], a0.w[dw], 0x05040100u);
        unsigned int hi = __builtin_amdgcn_perm(a1.w[dw], a0.w[dw], 0x07060302u);
        *(unsigned int*)&Vt[(vt_d0 + dw * 2) * 72 + vt_kk] = lo;
        *(unsigned int*)&Vt[(vt_d0 + dw * 2 + 1) * 72 + vt_kk] = hi;
    }
}

__global__ __launch_bounds__(256) void attn(const unsigned short* __restrict__ qkv,
                                            unsigned short* __restrict__ ob) {
    __shared__ __align__(16) unsigned short Ks[2][64 * 64];   // double-buffered, DMA-staged
    __shared__ __align__(16) unsigned short Vt[64 * 72];      // single (write/read same iter)
    __shared__ __align__(16) unsigned short Ps[4][16 * 72];

    const int head = blockIdx.x >> 1;
    const int d = blockIdx.x & 1;
    const int t0 = blockIdx.y * 2, t1 = t0 + 1;     // q-tile pair
    const int tid = threadIdx.x;
    const int lane = tid & 63, wv = tid >> 6;
    const int quad = lane >> 4, r16 = lane & 15;

    const unsigned short* qb = qkv;
    const unsigned short* kb = qkv + (size_t)S_ORIG * DIM;
    const unsigned short* vb = qkv + (size_t)2 * S_ORIG * DIM;

    // --- this lane's queries (B-operand of S^T), both tiles of the pair ---
    const int qi0 = t0 * 64 + wv * 16 + r16;
    const int qi1 = qi0 + 64;
    const int og_q0 = ((qi0 >> 8) << 9) + d * 256 + (qi0 & 255);
    const int og_q1 = ((qi1 >> 8) << 9) + d * 256 + (qi1 & 255);
    short8 qf0[2], qf1[2];
    {
        const float QSC = 0.125f * 1.44269504088896f;   // softmax scale * log2(e)
        const unsigned short* qr0 = qb + (size_t)og_q0 * DIM + head * HD + quad * 8;
        const unsigned short* qr1 = qb + (size_t)og_q1 * DIM + head * HD + quad * 8;
#pragma unroll
        for (int c = 0; c < 2; c++) {
            union { int4 i4; unsigned short u[8]; short8 s8; } i0v, i1v, a0v, a1v;
            i0v.i4 = *(const int4*)(qr0 + c * 32);
            i1v.i4 = *(const int4*)(qr1 + c * 32);
#pragma unroll
            for (int j = 0; j < 8; j++) {
                a0v.u[j] = f2bf(bf2f(i0v.u[j]) * QSC);
                a1v.u[j] = f2bf(bf2f(i1v.u[j]) * QSC);
            }
            qf0[c] = a0v.s8;
            qf1[c] = a1v.s8;
        }
    }

    f32x4 oacc0[4], oacc1[4];
    float lsum0 = 0.0f, lsum1 = 0.0f;
#pragma unroll
    for (int nt = 0; nt < 4; nt++)
#pragma unroll
        for (int rr = 0; rr < 4; rr++) { oacc0[nt][rr] = 0.0f; oacc1[nt][rr] = 0.0f; }

    // union of both windows, real tiles only (kt>=68 all-zero pad handled analytically)
    const int kt_lo = (t0 - 8 > 0) ? (t0 - 8) : 0;
    const int kt_hi = (t1 + 8 < 67) ? (t1 + 8) : 67;

    // K staging via GLD_LDS: chunk c = h*256 + tid; row = c>>3, physical slot c&7 holds
    // global chunk (c&7)^(row&7). Wave-uniform LDS base, per-lane swizzled source.
    const int krow0 = tid >> 3;                          // h=0 rows 0..31; h=1: +32
    const int kgc = ((tid & 7) ^ (krow0 & 7)) * 8;       // source chunk elem offset

    // V^T staging coords
    const int vt_kk = (tid & 31) * 2, vt_d0 = (tid >> 5) * 8;

    // frag-read swizzled chunk offsets: global chunk j of row r lives at j^(r&7)
    const int jsw0 = (quad ^ (r16 & 7)) * 8;
    const int jsw1 = jsw0 ^ 32;

    unsigned short* pw = &Ps[wv][0];

// issue K DMA for tile at kbase_ into buffer base bufb_ (2 GLD_LDS per thread-group)
#define ISSUE_K(kbase_, bufb_) do {                                              \
        const int kj0_ = (kbase_) + krow0;                                       \
        const int ok0_ = ((kj0_ >> 8) << 9) + d * 256 + (kj0_ & 255);            \
        GLD_LDS(kb + (size_t)ok0_ * DIM + head * HD + kgc, (bufb_) + wv * 512);  \
        const int kj1_ = kj0_ + 32;                                              \
        const int ok1_ = ((kj1_ >> 8) << 9) + d * 256 + (kj1_ & 255);            \
        GLD_LDS(kb + (size_t)ok1_ * DIM + head * HD + kgc, (bufb_) + 2048 + wv * 512); \
    } while (0)

// issue V global loads (2x dwordx4) for tile at kbase_ into regs a0_, a1_
#define LOAD_V(kbase_, a0_, a1_) do {                                            \
        const int kj_ = (kbase_) + vt_kk;                                        \
        const int ok_ = ((kj_ >> 8) << 9) + d * 256 + (kj_ & 255);               \
        (a0_) = *(const int4*)(vb + (size_t)ok_ * DIM + head * HD + vt_d0);      \
        (a1_) = *(const int4*)(vb + (size_t)(ok_ + 1) * DIM + head * HD + vt_d0);\
    } while (0)

    // prologue: tile kt_lo in flight (4 vector-mem ops outstanding)
    ISSUE_K(kt_lo * 64, &Ks[0][0]);
    int4 vc0, vc1;
    LOAD_V(kt_lo * 64, vc0, vc1);

    int cur = 0;
    for (int kt = kt_lo; kt <= kt_hi; kt++) {
        const int kbase = kt * 64;
        FBAR();   // A: all waves done reading Ks[cur^1] (prev compute) before DMA refill

        // issue NEXT tile (last iter: redundant re-issue keeps vmcnt count static)
        const int knb = ((kt < kt_hi) ? (kt + 1) : kt_hi) * 64;
        ISSUE_K(knb, &Ks[cur ^ 1][0]);
        int4 vn0, vn1;
        LOAD_V(knb, vn0, vn1);

        // counted wait: 4 newer ops in flight -> previous tile's 4 (K-DMA cur, V regs) done
        __asm__ volatile("s_waitcnt vmcnt(4)" ::: "memory");
        __builtin_amdgcn_sched_barrier(0);

        // stage V (current tile) into LDS: perm halfword merge + 8 dword stores
        pack_write_v(&Vt[0], vc0, vc1, vt_d0, vt_kk);
        __asm__ volatile("s_waitcnt lgkmcnt(0)" ::: "memory");
        FBAR();   // B: K[cur] DMA-resident + all waves' Vt writes visible

        // qset0 active for kt in [t0-8, t0+8]; qset1 for [t1-8, t1+8]; both uniform
        if (kt <= t0 + 8)
            qstep(&Ks[cur][0], Vt, pw, jsw0, jsw1, quad, r16, kbase, qi0,
                  (kt == t0 - 8) || (kt == t0 + 8), qf0, oacc0, lsum0);
        if (kt >= t1 - 8)
            qstep(&Ks[cur][0], Vt, pw, jsw0, jsw1, quad, r16, kbase, qi1,
                  (kt == t1 - 8) || (kt == t1 + 8), qf1, oacc1, lsum1);

        vc0 = vn0; vc1 = vn1;
        cur ^= 1;
    }
#undef ISSUE_K
#undef LOAD_V

    // keep the final (unused) V loads live so the per-iter vmcnt arithmetic above is
    // not perturbed by DCE (rule #17), then drain the dangling DMA before epilogue.
    __asm__ volatile("" :: "v"(vc0.x), "v"(vc0.y), "v"(vc0.z), "v"(vc0.w),
                          "v"(vc1.x), "v"(vc1.y), "v"(vc1.z), "v"(vc1.w));
    __asm__ volatile("s_waitcnt vmcnt(0)" ::: "memory");

    // --- final l: reduce across the 4 quads (other lanes hold other kk of same q) ---
    lsum0 += __shfl_xor(lsum0, 16, 64);
    lsum0 += __shfl_xor(lsum0, 32, 64);
    lsum1 += __shfl_xor(lsum1, 16, 64);
    lsum1 += __shfl_xor(lsum1, 32, 64);
    // zero-pad keys (dilated pos >= 4352 -> orig >= 8704, K=V=0): score 0 -> exp2(0)=1
    {
        const int cnt0 = (qi0 + WIN < 4607 ? qi0 + WIN : 4607) - 4351;
        if (cnt0 > 0) lsum0 += (float)cnt0;
        const int cnt1 = (qi1 + WIN < 4607 ? qi1 + WIN : 4607) - 4351;
        if (cnt1 > 0) lsum1 += (float)cnt1;
    }
    const float linv0 = 1.0f / lsum0;
    const float linv1 = 1.0f / lsum1;

    // --- write O: lane owns q = r16; 4 consecutive dims per nt; both qsets ---
#pragma unroll
    for (int nt = 0; nt < 4; nt++) {
        ushort4 o0, o1;
        o0.x = f2bf(oacc0[nt][0] * linv0);
        o0.y = f2bf(oacc0[nt][1] * linv0);
        o0.z = f2bf(oacc0[nt][2] * linv0);
        o0.w = f2bf(oacc0[nt][3] * linv0);
        *(ushort4*)&ob[(size_t)og_q0 * DIM + head * HD + nt * 16 + quad * 4] = o0;
        o1.x = f2bf(oacc1[nt][0] * linv1);
        o1.y = f2bf(oacc1[nt][1] * linv1);
        o1.z = f2bf(oacc1[nt][2] * linv1);
        o1.w = f2bf(oacc1[nt][3] * linv1);
        *(ushort4*)&ob[(size_t)og_q1 * DIM + head * HD + nt * 16 + quad * 4] = o1;
    }
}

// ---------------- launch ----------------
extern "C" void kernel_launch(void* const* d_in, const int* in_sizes, int n_in,
                              void* d_out, int out_size, void* d_ws, size_t ws_size,
                              hipStream_t stream) {
    const float* x    = (const float*)d_in[0];
    const float* fcos = (const float*)d_in[1];
    const float* fsin = (const float*)d_in[2];
    const float* wq   = (const float*)d_in[3];
    const float* bq   = (const float*)d_in[4];
    const float* wk   = (const float*)d_in[5];
    const float* bk   = (const float*)d_in[6];
    const float* wv   = (const float*)d_in[7];
    const float* bv   = (const float*)d_in[8];
    const float* wo   = (const float*)d_in[9];
    const float* bo   = (const float*)d_in[10];
    const float* gq   = (const float*)d_in[11];
    const float* gk   = (const float*)d_in[12];

    char* ws = (char*)d_ws;
    unsigned short* xb = (unsigned short*)(ws);
    unsigned short* wt = (unsigned short*)(ws + 17825792);
    unsigned short* h  = (unsigned short*)(ws + 26214400);
    unsigned short* ob = (unsigned short*)(ws + 79691776);
    float* outp = (float*)d_out;

    prep<<<9728, 256, 0, stream>>>(x, xb, wq, wk, wv, wo, wt);
    gemm_bf16<0><<<dim3(68, 8, 3), 256, 0, stream>>>(xb, wt, bq, bk, bv, (void*)h);
    norm_rope<<<dim3(2176, 2), 256, 0, stream>>>(h, h + (size_t)S_ORIG * DIM, gq, gk, fcos, fsin);
    attn<<<dim3(32, 34), 256, 0, stream>>>(h, ob);
    gemm_bf16<1><<<dim3(68, 8, 1), 256, 0, stream>>>(ob, wt + (size_t)3 * DIM * DIM, bo, bo, bo, (void*)outp);
}

// Round 5
// 302.583 us; speedup vs baseline: 1.0812x; 1.0318x over previous
//
#include <hip/hip_runtime.h>
#include <hip/hip_bf16.h>
#include <stdint.h>

// Problem constants (shapes fixed by the reference)
#define DIM 1024
#define NH 16
#define HD 64
#define S_ORIG 8704
#define WIN 512          // L * WINDOW = 256*2

typedef __attribute__((ext_vector_type(8))) short short8;
typedef __attribute__((ext_vector_type(4))) float f32x4;

__device__ __forceinline__ float bf2f(unsigned short u) {
    return __uint_as_float(((unsigned int)u) << 16);
}
__device__ __forceinline__ unsigned short f2bf(float f) {
    unsigned int x = __float_as_uint(f);
    unsigned int r = x + 0x7fffu + ((x >> 16) & 1u);   // RNE
    return (unsigned short)(r >> 16);
}
// two fp32 -> packed bf16x2 in ONE VALU op (T12 recipe; no builtin on gfx950)
__device__ __forceinline__ unsigned int cvtpk(float lo, float hi) {
    unsigned int r;
    asm("v_cvt_pk_bf16_f32 %0, %1, %2" : "=v"(r) : "v"(lo), "v"(hi));
    return r;
}
// exp2 in a single v_exp_f32 (log2e folded into the Q scale by the caller)
__device__ __forceinline__ float fexp2(float x) {
#if __has_builtin(__builtin_amdgcn_exp2f)
    return __builtin_amdgcn_exp2f(x);
#else
    float r;
    asm("v_exp_f32 %0, %1" : "=v"(r) : "v"(x));
    return r;
#endif
}

#define GLD_LDS(gptr, lptr) \
    __builtin_amdgcn_global_load_lds((const __attribute__((address_space(1))) void*)(gptr), \
                                     (__attribute__((address_space(3))) void*)(lptr), 16, 0, 0)

// raw barrier (no compiler-inserted full drains) with compiler memory fences
#define FBAR() do { __asm__ volatile("" ::: "memory"); \
                    __builtin_amdgcn_s_barrier(); \
                    __asm__ volatile("" ::: "memory"); } while (0)

// ---------------- merged prep: fp32->bf16 convert (x) + weight transpose ----------------
// blocks [0, 8704): cvt; blocks [8704, 9728): transpose (one launch, one less bubble)
__global__ __launch_bounds__(256) void prep(const float* __restrict__ x,
                                            unsigned short* __restrict__ xb,
                                            const float* __restrict__ w0,
                                            const float* __restrict__ w1,
                                            const float* __restrict__ w2,
                                            const float* __restrict__ w3,
                                            unsigned short* __restrict__ wt) {
    __shared__ float ts[64][65];
    const int bx = blockIdx.x;
    const int t = threadIdx.x;
    if (bx < 8704) {
        int i = (bx * 256 + t) * 4;   // total = 8704*1024, exact
        float4 v = *(const float4*)(x + i);
        ushort4 o;
        o.x = f2bf(v.x); o.y = f2bf(v.y); o.z = f2bf(v.z); o.w = f2bf(v.w);
        *(ushort4*)(xb + i) = o;
        return;
    }
    const int b = bx - 8704;
    const int z = b >> 8;
    const int rem = b & 255;
    const int kb = (rem >> 4) * 64, nb = (rem & 15) * 64;
    const float* w = z == 0 ? w0 : z == 1 ? w1 : z == 2 ? w2 : w3;
    unsigned short* o = wt + (size_t)z * DIM * DIM;
    const int c = t & 63, r4 = t >> 6;
#pragma unroll
    for (int rr = 0; rr < 16; rr++) {
        int row = rr * 4 + r4;
        ts[row][c] = w[(size_t)(kb + row) * DIM + nb + c];
    }
    __syncthreads();
#pragma unroll
    for (int rr = 0; rr < 16; rr++) {
        int nl = rr * 4 + r4;
        o[(size_t)(nb + nl) * DIM + kb + c] = f2bf(ts[c][nl]);
    }
}

// ---------------- bf16 MFMA GEMM: C[M,N] = A[M,K] * Bt[N,K]^T + bias ----------------
// R5: 3-deep pipelined staging (R4 attn trick generalized). Each BK=32 step's 4 GLD_LDS
// (2 A + 2 B) are issued two steps ahead into a rotating 3-buffer; counted
// s_waitcnt vmcnt(8) (= 2 newer steps x 4 ops) replaces the vmcnt(0) drain, so HBM/L2
// latency leaves the per-step critical path. Tail peeled with vmcnt(4)/vmcnt(0).
// 128x128 tile, 4 waves, XOR bank swizzle, m-fastest grid (XCD A-strip locality).
__device__ __forceinline__ void gemm_step(const unsigned short* __restrict__ pa,
                                          const unsigned short* __restrict__ pb,
                                          int wr, int wc, int r, int jsw,
                                          f32x4 acc[4][4]) {
    short8 af[4], bfr[4];
#pragma unroll
    for (int i = 0; i < 4; i++)
        af[i] = *(const short8*)&pa[(wr * 64 + i * 16 + r) * 32 + jsw];
#pragma unroll
    for (int j = 0; j < 4; j++)
        bfr[j] = *(const short8*)&pb[(wc * 64 + j * 16 + r) * 32 + jsw];
#pragma unroll
    for (int i = 0; i < 4; i++)
#pragma unroll
        for (int j = 0; j < 4; j++)
            acc[i][j] = __builtin_amdgcn_mfma_f32_16x16x32_bf16(af[i], bfr[j], acc[i][j], 0, 0, 0);
}

template <int OUTF32>
__global__ __launch_bounds__(256) void gemm_bf16(const unsigned short* __restrict__ A,
                                                 const unsigned short* __restrict__ Bt,
                                                 const float* __restrict__ b0,
                                                 const float* __restrict__ b1,
                                                 const float* __restrict__ b2,
                                                 void* __restrict__ Cout) {
    __shared__ __align__(16) unsigned short As[3][128 * 32];
    __shared__ __align__(16) unsigned short Bs[3][128 * 32];
    const int z = blockIdx.z;
    const unsigned short* B = Bt + (size_t)z * DIM * DIM;
    const float* bias = z == 0 ? b0 : (z == 1 ? b1 : b2);
    const int m0 = blockIdx.x * 128, n0 = blockIdx.y * 128;   // m fastest (XCD locality)
    const int tid = threadIdx.x;
    const int lane = tid & 63, wv = tid >> 6;
    const int wr = wv >> 1, wc = wv & 1;
    const int quad = lane >> 4, r = lane & 15;

    f32x4 acc[4][4];
#pragma unroll
    for (int i = 0; i < 4; i++)
#pragma unroll
        for (int j = 0; j < 4; j++)
#pragma unroll
            for (int t4 = 0; t4 < 4; t4++) acc[i][j][t4] = 0.0f;

    const unsigned short* a_base = A + (size_t)m0 * DIM;
    const unsigned short* b_base = B + (size_t)n0 * DIM;
    // staging chunk c (16B): row = c>>2, physical slot c&3; holds global col-chunk
    // gc = (c&3) ^ ((c>>3)&3). Per-wave GLD instr i covers slots wv*128 + i*64 + lane.
    const int c0 = wv * 128 + lane;
    const int r0 = c0 >> 2, o0 = (((c0 & 3) ^ ((c0 >> 3) & 3))) * 8;
    const int c1 = c0 + 64;
    const int r1 = c1 >> 2, o1 = (((c1 & 3) ^ ((c1 >> 3) & 3))) * 8;
    const int ld0 = (wv * 128) * 8, ld1 = (wv * 128 + 64) * 8;

    // frag-read physical chunk: quad ^ ((row>>1)&3) == quad ^ ((r>>1)&3) (base mult of 16)
    const int jsw = (quad ^ ((r >> 1) & 3)) * 8;

#define ISSUE_STEP(k0_, abuf_, bbuf_) do {                                  \
        GLD_LDS(a_base + (size_t)r0 * DIM + (k0_) + o0, (abuf_) + ld0);     \
        GLD_LDS(a_base + (size_t)r1 * DIM + (k0_) + o1, (abuf_) + ld1);     \
        GLD_LDS(b_base + (size_t)r0 * DIM + (k0_) + o0, (bbuf_) + ld0);     \
        GLD_LDS(b_base + (size_t)r1 * DIM + (k0_) + o1, (bbuf_) + ld1);     \
    } while (0)

    unsigned short *pa0 = &As[0][0], *pa1 = &As[1][0], *pa2 = &As[2][0];
    unsigned short *pb0 = &Bs[0][0], *pb1 = &Bs[1][0], *pb2 = &Bs[2][0];

    // prologue: steps 0 and 32 in flight (8 vmem ops outstanding)
    ISSUE_STEP(0, pa0, pb0);
    ISSUE_STEP(32, pa1, pb1);

#pragma unroll 3
    for (int k0 = 0; k0 < DIM - 64; k0 += 32) {
        FBAR();   // all waves done reading the buffer pa2/pb2 (computed last iter)
        ISSUE_STEP(k0 + 64, pa2, pb2);
        __asm__ volatile("s_waitcnt vmcnt(8)" ::: "memory");   // step k0's 4 ops done
        __builtin_amdgcn_sched_barrier(0);
        FBAR();   // all waves' DMAs for step k0 landed
        gemm_step(pa0, pb0, wr, wc, r, jsw, acc);
        unsigned short* t;
        t = pa0; pa0 = pa1; pa1 = pa2; pa2 = t;
        t = pb0; pb0 = pb1; pb1 = pb2; pb2 = t;
    }
    // peeled tail: no new issues; counted waits shrink 4 -> 0
    __asm__ volatile("s_waitcnt vmcnt(4)" ::: "memory");
    __builtin_amdgcn_sched_barrier(0);
    FBAR();
    gemm_step(pa0, pb0, wr, wc, r, jsw, acc);
    {
        unsigned short* t;
        t = pa0; pa0 = pa1; pa1 = pa2; pa2 = t;
        t = pb0; pb0 = pb1; pb1 = pb2; pb2 = t;
    }
    __asm__ volatile("s_waitcnt vmcnt(0)" ::: "memory");
    __builtin_amdgcn_sched_barrier(0);
    FBAR();
    gemm_step(pa0, pb0, wr, wc, r, jsw, acc);
#undef ISSUE_STEP

    // epilogue: C/D layout col = lane&15, row = quad*4 + reg
#pragma unroll
    for (int i = 0; i < 4; i++) {
        const int row = m0 + wr * 64 + i * 16 + quad * 4;
#pragma unroll
        for (int j = 0; j < 4; j++) {
            const int col = n0 + wc * 64 + j * 16 + r;
            const float bvl = bias[col];
#pragma unroll
            for (int t4 = 0; t4 < 4; t4++) {
                float vv = acc[i][j][t4] + bvl;
                if (OUTF32) {
                    ((float*)Cout)[(size_t)(row + t4) * DIM + col] = vv;
                } else {
                    ((unsigned short*)Cout)[(size_t)z * S_ORIG * DIM + (size_t)(row + t4) * DIM + col] = f2bf(vv);
                }
            }
        }
    }
}

// ---------------- fused RMSNorm + RoPE, wave-per-row (no LDS, no barrier) ----------------
__global__ __launch_bounds__(256) void norm_rope(unsigned short* __restrict__ hq,
                                                 unsigned short* __restrict__ hk,
                                                 const float* __restrict__ gq,
                                                 const float* __restrict__ gk,
                                                 const float* __restrict__ fcos,
                                                 const float* __restrict__ fsin) {
    const int z = blockIdx.y;
    unsigned short* h = z == 0 ? hq : hk;
    const float* g = z == 0 ? gq : gk;
    const int w = threadIdx.x >> 6, lane = threadIdx.x & 63;
    const int srow = blockIdx.x * 4 + w;
    unsigned short* hp = h + (size_t)srow * DIM;
    const int p0 = lane * 8, p1 = 512 + lane * 8;

    union { int4 i4; unsigned short u[8]; } r0, r1, o0, o1;
    r0.i4 = *(const int4*)(hp + p0);
    r1.i4 = *(const int4*)(hp + p1);
    float v[16];
#pragma unroll
    for (int j = 0; j < 8; j++) { v[j] = bf2f(r0.u[j]); v[8 + j] = bf2f(r1.u[j]); }

    float ss = 0.0f;
#pragma unroll
    for (int j = 0; j < 16; j++) ss += v[j] * v[j];
#pragma unroll
    for (int off = 1; off < 64; off <<= 1) ss += __shfl_xor(ss, off, 64);
    const float rinv = rsqrtf(ss * (1.0f / DIM) + 1e-6f);

    float4 ga = *(const float4*)(g + p0), gb = *(const float4*)(g + p0 + 4);
    float4 gc = *(const float4*)(g + p1), gd = *(const float4*)(g + p1 + 4);
    const float* gg[4] = {&ga.x, &gb.x, &gc.x, &gd.x};
#pragma unroll
    for (int q4 = 0; q4 < 4; q4++)
#pragma unroll
        for (int j = 0; j < 4; j++) v[q4 * 4 + j] *= rinv * gg[q4][j];

    const int i0 = (p0 & 63) >> 1;   // pair base within head (mult of 4); same for p1
    float4 cs = *(const float4*)(fcos + (size_t)srow * 32 + i0);
    float4 sn = *(const float4*)(fsin + (size_t)srow * 32 + i0);
    const float* cp = &cs.x;
    const float* sp = &sn.x;
#pragma unroll
    for (int seg = 0; seg < 2; seg++) {
        unsigned short* uo = seg == 0 ? o0.u : o1.u;
#pragma unroll
        for (int pr = 0; pr < 4; pr++) {
            const float a = v[seg * 8 + pr * 2], b = v[seg * 8 + pr * 2 + 1];
            uo[pr * 2]     = f2bf(a * cp[pr] - b * sp[pr]);
            uo[pr * 2 + 1] = f2bf(a * sp[pr] + b * cp[pr]);
        }
    }
    *(int4*)(hp + p0) = o0.i4;
    *(int4*)(hp + p1) = o1.i4;
}

// ---------------- dilated sliding-window attention, transposed-MFMA flash ----------------
// R4 structure (verified): K double-buffered via GLD_LDS DMA; V global loads issued one
// tile ahead into registers; counted s_waitcnt vmcnt(4); raw barriers; two q-tiles per
// block. Per-lane softmax via swapped QK^T; fixed-max exp2 (log2e folded in Q scale);
// zero-pad keys (kt>=68) contribute l analytically.
__device__ __forceinline__ void qstep(const unsigned short* __restrict__ Ks,
                                      const unsigned short* __restrict__ Vt,
                                      unsigned short* __restrict__ pw,
                                      int jsw0, int jsw1, int quad, int r16,
                                      int kbase, int qi, bool edge,
                                      const short8* __restrict__ qf,
                                      f32x4* __restrict__ oacc, float& lsum) {
    // --- S^T[kk][q]: A-op = K rows (swizzled read), B-op = Q frag ---
    f32x4 sv[4];
#pragma unroll
    for (int nt = 0; nt < 4; nt++) {
        const int row = (nt * 16 + r16) * 64;
        short8 k0f = *(const short8*)&Ks[row + jsw0];
        short8 k1f = *(const short8*)&Ks[row + jsw1];
        f32x4 a = {0.0f, 0.0f, 0.0f, 0.0f};
        a = __builtin_amdgcn_mfma_f32_16x16x32_bf16(k0f, qf[0], a, 0, 0, 0);
        a = __builtin_amdgcn_mfma_f32_16x16x32_bf16(k1f, qf[1], a, 0, 0, 0);
        sv[nt] = a;
    }
    // --- exp2 (no max subtraction: scores bounded), mask on edge tiles only ---
#pragma unroll
    for (int nt = 0; nt < 4; nt++) {
        float p[4];
#pragma unroll
        for (int rr = 0; rr < 4; rr++) {
            float e = fexp2(sv[nt][rr]);
            if (edge) {
                const int kj = kbase + nt * 16 + quad * 4 + rr;
                const int dl = qi - kj;
                if (dl > WIN || dl < -WIN) e = 0.0f;
            }
            p[rr] = e;
        }
        lsum += (p[0] + p[1]) + (p[2] + p[3]);
        uint2 pk;
        pk.x = cvtpk(p[0], p[1]);
        pk.y = cvtpk(p[2], p[3]);
        *(uint2*)&pw[r16 * 72 + nt * 16 + quad * 4] = pk;
    }
    __asm__ volatile("s_waitcnt lgkmcnt(0)" ::: "memory");
    // --- O^T += V^T * P^T ---
    short8 pf0 = *(const short8*)&pw[r16 * 72 + quad * 8];
    short8 pf1 = *(const short8*)&pw[r16 * 72 + 32 + quad * 8];
#pragma unroll
    for (int nt = 0; nt < 4; nt++) {
        short8 v0f = *(const short8*)&Vt[(nt * 16 + r16) * 72 + quad * 8];
        short8 v1f = *(const short8*)&Vt[(nt * 16 + r16) * 72 + 32 + quad * 8];
        oacc[nt] = __builtin_amdgcn_mfma_f32_16x16x32_bf16(v0f, pf0, oacc[nt], 0, 0, 0);
        oacc[nt] = __builtin_amdgcn_mfma_f32_16x16x32_bf16(v1f, pf1, oacc[nt], 0, 0, 0);
    }
}

__device__ __forceinline__ void pack_write_v(unsigned short* __restrict__ Vt,
                                             int4 a0i, int4 a1i, int vt_d0, int vt_kk) {
    union { int4 i4; unsigned int w[4]; } a0, a1;
    a0.i4 = a0i; a1.i4 = a1i;
#pragma unroll
    for (int dw = 0; dw < 4; dw++) {
        unsigned int lo = __builtin_amdgcn_perm(a1.w[dw], a0.w[dw], 0x05040100u);
        unsigned int hi = __builtin_amdgcn_perm(a1.w[dw], a0.w[dw], 0x07060302u);
        *(unsigned int*)&Vt[(vt_d0 + dw * 2) * 72 + vt_kk] = lo;
        *(unsigned int*)&Vt[(vt_d0 + dw * 2 + 1) * 72 + vt_kk] = hi;
    }
}

__global__ __launch_bounds__(256) void attn(const unsigned short* __restrict__ qkv,
                                            unsigned short* __restrict__ ob) {
    __shared__ __align__(16) unsigned short Ks[2][64 * 64];   // double-buffered, DMA-staged
    __shared__ __align__(16) unsigned short Vt[64 * 72];      // single (write/read same iter)
    __shared__ __align__(16) unsigned short Ps[4][16 * 72];

    const int head = blockIdx.x >> 1;
    const int d = blockIdx.x & 1;
    const int t0 = blockIdx.y * 2, t1 = t0 + 1;     // q-tile pair
    const int tid = threadIdx.x;
    const int lane = tid & 63, wv = tid >> 6;
    const int quad = lane >> 4, r16 = lane & 15;

    const unsigned short* qb = qkv;
    const unsigned short* kb = qkv + (size_t)S_ORIG * DIM;
    const unsigned short* vb = qkv + (size_t)2 * S_ORIG * DIM;

    // --- this lane's queries (B-operand of S^T), both tiles of the pair ---
    const int qi0 = t0 * 64 + wv * 16 + r16;
    const int qi1 = qi0 + 64;
    const int og_q0 = ((qi0 >> 8) << 9) + d * 256 + (qi0 & 255);
    const int og_q1 = ((qi1 >> 8) << 9) + d * 256 + (qi1 & 255);
    short8 qf0[2], qf1[2];
    {
        const float QSC = 0.125f * 1.44269504088896f;   // softmax scale * log2(e)
        const unsigned short* qr0 = qb + (size_t)og_q0 * DIM + head * HD + quad * 8;
        const unsigned short* qr1 = qb + (size_t)og_q1 * DIM + head * HD + quad * 8;
#pragma unroll
        for (int c = 0; c < 2; c++) {
            union { int4 i4; unsigned short u[8]; short8 s8; } i0v, i1v, a0v, a1v;
            i0v.i4 = *(const int4*)(qr0 + c * 32);
            i1v.i4 = *(const int4*)(qr1 + c * 32);
#pragma unroll
            for (int j = 0; j < 8; j++) {
                a0v.u[j] = f2bf(bf2f(i0v.u[j]) * QSC);
                a1v.u[j] = f2bf(bf2f(i1v.u[j]) * QSC);
            }
            qf0[c] = a0v.s8;
            qf1[c] = a1v.s8;
        }
    }

    f32x4 oacc0[4], oacc1[4];
    float lsum0 = 0.0f, lsum1 = 0.0f;
#pragma unroll
    for (int nt = 0; nt < 4; nt++)
#pragma unroll
        for (int rr = 0; rr < 4; rr++) { oacc0[nt][rr] = 0.0f; oacc1[nt][rr] = 0.0f; }

    // union of both windows, real tiles only (kt>=68 all-zero pad handled analytically)
    const int kt_lo = (t0 - 8 > 0) ? (t0 - 8) : 0;
    const int kt_hi = (t1 + 8 < 67) ? (t1 + 8) : 67;

    // K staging via GLD_LDS: chunk c = h*256 + tid; row = c>>3, physical slot c&7 holds
    // global chunk (c&7)^(row&7). Wave-uniform LDS base, per-lane swizzled source.
    const int krow0 = tid >> 3;                          // h=0 rows 0..31; h=1: +32
    const int kgc = ((tid & 7) ^ (krow0 & 7)) * 8;       // source chunk elem offset

    // V^T staging coords
    const int vt_kk = (tid & 31) * 2, vt_d0 = (tid >> 5) * 8;

    // frag-read swizzled chunk offsets: global chunk j of row r lives at j^(r&7)
    const int jsw0 = (quad ^ (r16 & 7)) * 8;
    const int jsw1 = jsw0 ^ 32;

    unsigned short* pw = &Ps[wv][0];

// issue K DMA for tile at kbase_ into buffer base bufb_ (2 GLD_LDS per thread-group)
#define ISSUE_K(kbase_, bufb_) do {                                              \
        const int kj0_ = (kbase_) + krow0;                                       \
        const int ok0_ = ((kj0_ >> 8) << 9) + d * 256 + (kj0_ & 255);            \
        GLD_LDS(kb + (size_t)ok0_ * DIM + head * HD + kgc, (bufb_) + wv * 512);  \
        const int kj1_ = kj0_ + 32;                                              \
        const int ok1_ = ((kj1_ >> 8) << 9) + d * 256 + (kj1_ & 255);            \
        GLD_LDS(kb + (size_t)ok1_ * DIM + head * HD + kgc, (bufb_) + 2048 + wv * 512); \
    } while (0)

// issue V global loads (2x dwordx4) for tile at kbase_ into regs a0_, a1_
#define LOAD_V(kbase_, a0_, a1_) do {                                            \
        const int kj_ = (kbase_) + vt_kk;                                        \
        const int ok_ = ((kj_ >> 8) << 9) + d * 256 + (kj_ & 255);               \
        (a0_) = *(const int4*)(vb + (size_t)ok_ * DIM + head * HD + vt_d0);      \
        (a1_) = *(const int4*)(vb + (size_t)(ok_ + 1) * DIM + head * HD + vt_d0);\
    } while (0)

    // prologue: tile kt_lo in flight (4 vector-mem ops outstanding)
    ISSUE_K(kt_lo * 64, &Ks[0][0]);
    int4 vc0, vc1;
    LOAD_V(kt_lo * 64, vc0, vc1);

    int cur = 0;
    for (int kt = kt_lo; kt <= kt_hi; kt++) {
        const int kbase = kt * 64;
        FBAR();   // A: all waves done reading Ks[cur^1] (prev compute) before DMA refill

        // issue NEXT tile (last iter: redundant re-issue keeps vmcnt count static)
        const int knb = ((kt < kt_hi) ? (kt + 1) : kt_hi) * 64;
        ISSUE_K(knb, &Ks[cur ^ 1][0]);
        int4 vn0, vn1;
        LOAD_V(knb, vn0, vn1);

        // counted wait: 4 newer ops in flight -> previous tile's 4 (K-DMA cur, V regs) done
        __asm__ volatile("s_waitcnt vmcnt(4)" ::: "memory");
        __builtin_amdgcn_sched_barrier(0);

        // stage V (current tile) into LDS: perm halfword merge + 8 dword stores
        pack_write_v(&Vt[0], vc0, vc1, vt_d0, vt_kk);
        __asm__ volatile("s_waitcnt lgkmcnt(0)" ::: "memory");
        FBAR();   // B: K[cur] DMA-resident + all waves' Vt writes visible

        // qset0 active for kt in [t0-8, t0+8]; qset1 for [t1-8, t1+8]; both uniform
        if (kt <= t0 + 8)
            qstep(&Ks[cur][0], Vt, pw, jsw0, jsw1, quad, r16, kbase, qi0,
                  (kt == t0 - 8) || (kt == t0 + 8), qf0, oacc0, lsum0);
        if (kt >= t1 - 8)
            qstep(&Ks[cur][0], Vt, pw, jsw0, jsw1, quad, r16, kbase, qi1,
                  (kt == t1 - 8) || (kt == t1 + 8), qf1, oacc1, lsum1);

        vc0 = vn0; vc1 = vn1;
        cur ^= 1;
    }
#undef ISSUE_K
#undef LOAD_V

    // keep the final (unused) V loads live so the per-iter vmcnt arithmetic above is
    // not perturbed by DCE (rule #17), then drain the dangling DMA before epilogue.
    __asm__ volatile("" :: "v"(vc0.x), "v"(vc0.y), "v"(vc0.z), "v"(vc0.w),
                          "v"(vc1.x), "v"(vc1.y), "v"(vc1.z), "v"(vc1.w));
    __asm__ volatile("s_waitcnt vmcnt(0)" ::: "memory");

    // --- final l: reduce across the 4 quads (other lanes hold other kk of same q) ---
    lsum0 += __shfl_xor(lsum0, 16, 64);
    lsum0 += __shfl_xor(lsum0, 32, 64);
    lsum1 += __shfl_xor(lsum1, 16, 64);
    lsum1 += __shfl_xor(lsum1, 32, 64);
    // zero-pad keys (dilated pos >= 4352 -> orig >= 8704, K=V=0): score 0 -> exp2(0)=1
    {
        const int cnt0 = (qi0 + WIN < 4607 ? qi0 + WIN : 4607) - 4351;
        if (cnt0 > 0) lsum0 += (float)cnt0;
        const int cnt1 = (qi1 + WIN < 4607 ? qi1 + WIN : 4607) - 4351;
        if (cnt1 > 0) lsum1 += (float)cnt1;
    }
    const float linv0 = 1.0f / lsum0;
    const float linv1 = 1.0f / lsum1;

    // --- write O: lane owns q = r16; 4 consecutive dims per nt; both qsets ---
#pragma unroll
    for (int nt = 0; nt < 4; nt++) {
        ushort4 o0, o1;
        o0.x = f2bf(oacc0[nt][0] * linv0);
        o0.y = f2bf(oacc0[nt][1] * linv0);
        o0.z = f2bf(oacc0[nt][2] * linv0);
        o0.w = f2bf(oacc0[nt][3] * linv0);
        *(ushort4*)&ob[(size_t)og_q0 * DIM + head * HD + nt * 16 + quad * 4] = o0;
        o1.x = f2bf(oacc1[nt][0] * linv1);
        o1.y = f2bf(oacc1[nt][1] * linv1);
        o1.z = f2bf(oacc1[nt][2] * linv1);
        o1.w = f2bf(oacc1[nt][3] * linv1);
        *(ushort4*)&ob[(size_t)og_q1 * DIM + head * HD + nt * 16 + quad * 4] = o1;
    }
}

// ---------------- launch ----------------
extern "C" void kernel_launch(void* const* d_in, const int* in_sizes, int n_in,
                              void* d_out, int out_size, void* d_ws, size_t ws_size,
                              hipStream_t stream) {
    const float* x    = (const float*)d_in[0];
    const float* fcos = (const float*)d_in[1];
    const float* fsin = (const float*)d_in[2];
    const float* wq   = (const float*)d_in[3];
    const float* bq   = (const float*)d_in[4];
    const float* wk   = (const float*)d_in[5];
    const float* bk   = (const float*)d_in[6];
    const float* wv   = (const float*)d_in[7];
    const float* bv   = (const float*)d_in[8];
    const float* wo   = (const float*)d_in[9];
    const float* bo   = (const float*)d_in[10];
    const float* gq   = (const float*)d_in[11];
    const float* gk   = (const float*)d_in[12];

    char* ws = (char*)d_ws;
    unsigned short* xb = (unsigned short*)(ws);
    unsigned short* wt = (unsigned short*)(ws + 17825792);
    unsigned short* h  = (unsigned short*)(ws + 26214400);
    unsigned short* ob = (unsigned short*)(ws + 79691776);
    float* outp = (float*)d_out;

    prep<<<9728, 256, 0, stream>>>(x, xb, wq, wk, wv, wo, wt);
    gemm_bf16<0><<<dim3(68, 8, 3), 256, 0, stream>>>(xb, wt, bq, bk, bv, (void*)h);
    norm_rope<<<dim3(2176, 2), 256, 0, stream>>>(h, h + (size_t)S_ORIG * DIM, gq, gk, fcos, fsin);
    attn<<<dim3(32, 34), 256, 0, stream>>>(h, ob);
    gemm_bf16<1><<<dim3(68, 8, 1), 256, 0, stream>>>(ob, wt + (size_t)3 * DIM * DIM, bo, bo, bo, (void*)outp);
}